// Round 9
// baseline (230.213 us; speedup 1.0000x reference)
//
#include <hip/hip_runtime.h>

#define DEV __device__ __forceinline__

constexpr int B_  = 4;
constexpr int C_  = 256;
constexpr int C8_ = 32;
constexpr int N_  = 4096;   // 64*64
constexpr float LOG2E = 1.4426950408889634f;

using u16 = unsigned short;
using u32 = unsigned int;

typedef __attribute__((ext_vector_type(8))) short bf16x8;
typedef __attribute__((ext_vector_type(4))) float f32x4;

DEV float bf2f(u16 u) { return __uint_as_float(((u32)u) << 16); }
DEV u16   f2bf(float f) {
  u32 i = __float_as_uint(f);
  i += 0x7fffu + ((i >> 16) & 1u);   // round-to-nearest-even
  return (u16)(i >> 16);
}
// pack two floats to bf16x2 (RTZ) in ONE v_perm_b32
DEV u32 pack_rtz(float a, float b) {
  return __builtin_amdgcn_perm(__float_as_uint(b), __float_as_uint(a), 0x07060302);
}

// LDS-only barrier: cross-wave data is in LDS only -> skip the vmcnt(0) drain
DEV void lds_barrier() {
  asm volatile("s_waitcnt lgkmcnt(0)\n\ts_barrier" ::: "memory");
}

// ---------------------------------------------------------------------------
// Weight prep: Wq*log2e, Wk -> hi/lo; Wv -> hi only; Wo -> hi/lo.
// ---------------------------------------------------------------------------
__global__ __launch_bounds__(256) void wsplit(
    const float* __restrict__ Wq, const float* __restrict__ Wk,
    const float* __restrict__ Wv, const float* __restrict__ Wo,
    u16* __restrict__ WqH, u16* __restrict__ WqL,
    u16* __restrict__ WkH, u16* __restrict__ WkL,
    u16* __restrict__ WvH,
    u16* __restrict__ WoH, u16* __restrict__ WoL)
{
  int i = blockIdx.x * 256 + threadIdx.x;
  if (i < 8192) {
    float v = Wq[i] * LOG2E;
    u16 h = f2bf(v); WqH[i] = h; WqL[i] = f2bf(v - bf2f(h));
  } else if (i < 16384) {
    int off = i - 8192;
    float v = Wk[off];
    u16 h = f2bf(v); WkH[off] = h; WkL[off] = f2bf(v - bf2f(h));
  } else if (i < 81920) {
    int off = i - 16384;
    WvH[off] = f2bf(Wv[off]);
  } else {
    int off = i - 81920;
    float v = Wo[off];
    u16 h = f2bf(v); WoH[off] = h; WoL[off] = f2bf(v - bf2f(h));
  }
}

// ---------------------------------------------------------------------------
// x (B,C,N) f32 -> xTh, xTl (B,N,C) bf16 hi/lo (transpose via LDS).
// grid (N/64, C/64, B), block 256.
// ---------------------------------------------------------------------------
__global__ __launch_bounds__(256) void xprep(
    const float* __restrict__ x, u16* __restrict__ xTh, u16* __restrict__ xTl)
{
  __shared__ float tf[64][65];
  const int tid = threadIdx.x;
  const int b = blockIdx.z, c0 = blockIdx.y * 64, n0 = blockIdx.x * 64;
  const int nl = tid & 63, cb = tid >> 6;

  #pragma unroll
  for (int cc = 0; cc < 16; ++cc) {
    int cl = cb * 16 + cc;
    tf[nl][cl] = x[((size_t)b * C_ + c0 + cl) * N_ + n0 + nl];
  }
  __syncthreads();

  #pragma unroll
  for (int it = 0; it < 2; ++it) {
    int idx = tid + it * 256;
    int n = idx >> 3, q = idx & 7;
    u32 ph[4], pl[4];
    #pragma unroll
    for (int j = 0; j < 4; ++j) {
      float v0 = tf[n][q * 8 + 2 * j], v1 = tf[n][q * 8 + 2 * j + 1];
      u16 h0 = f2bf(v0), h1 = f2bf(v1);
      ph[j] = (u32)h0 | ((u32)h1 << 16);
      pl[j] = (u32)f2bf(v0 - bf2f(h0)) | ((u32)f2bf(v1 - bf2f(h1)) << 16);
    }
    size_t off = ((size_t)b * N_ + n0 + n) * C_ + c0 + q * 8;
    *(uint4*)&xTh[off] = make_uint4(ph[0], ph[1], ph[2], ph[3]);
    *(uint4*)&xTl[off] = make_uint4(pl[0], pl[1], pl[2], pl[3]);
  }
}

// ---------------------------------------------------------------------------
// q/k/v projections, LDS-staged x fragments.  16-pixel tiles.
// grid (N/16, B), block 256 -> 1024 blocks (4/CU).
// ---------------------------------------------------------------------------
__global__ __launch_bounds__(256) void qkv_mfma(
    const u16* __restrict__ xTh, const u16* __restrict__ xTl,
    const u16* __restrict__ WqH, const u16* __restrict__ WqL,
    const u16* __restrict__ WkH, const u16* __restrict__ WkL,
    const u16* __restrict__ WvH,
    const float* __restrict__ bq, const float* __restrict__ bk,
    const float* __restrict__ bv,
    u16* __restrict__ qt, u16* __restrict__ kt, u16* __restrict__ vb)
{
  __shared__ __align__(16) u16 xsh[16][270];
  __shared__ __align__(16) u16 xsl[16][270];

  const int tid = threadIdx.x;
  const int lane = tid & 63, w = tid >> 6, m = lane & 15, quad = lane >> 4;
  const int b = blockIdx.y, n0 = blockIdx.x * 16;

  #pragma unroll
  for (int it = 0; it < 2; ++it) {
    int chunk = tid + it * 256;
    int row = chunk >> 5, col = (chunk & 31) * 8;
    size_t g = ((size_t)b * N_ + n0 + row) * C_ + col;
    *(uint4*)&xsh[row][col] = *(const uint4*)(xTh + g);
    *(uint4*)&xsl[row][col] = *(const uint4*)(xTl + g);
  }
  __syncthreads();

  const u16* qkH = (w < 2) ? (WqH + (size_t)(w * 16 + m) * C_)
                           : (WkH + (size_t)((w - 2) * 16 + m) * C_);
  const u16* qkL = (w < 2) ? (WqL + (size_t)(w * 16 + m) * C_)
                           : (WkL + (size_t)((w - 2) * 16 + m) * C_);

  f32x4 ov[4], oq;
  #pragma unroll
  for (int dt = 0; dt < 4; ++dt) ov[dt] = (f32x4){0.f, 0.f, 0.f, 0.f};
  oq = (f32x4){0.f, 0.f, 0.f, 0.f};

  for (int K = 0; K < 8; ++K) {
    const int ko = K * 32 + quad * 8;
    bf16x8 xh = *(const bf16x8*)&xsh[m][ko];
    bf16x8 xl = *(const bf16x8*)&xsl[m][ko];
    #pragma unroll
    for (int dt = 0; dt < 4; ++dt) {
      bf16x8 whi = *(const bf16x8*)(WvH + (size_t)(64 * w + dt * 16 + m) * C_ + ko);
      ov[dt] = __builtin_amdgcn_mfma_f32_16x16x32_bf16(whi, xh, ov[dt], 0, 0, 0);
    }
    {
      bf16x8 bhi = *(const bf16x8*)(qkH + ko);
      bf16x8 blo = *(const bf16x8*)(qkL + ko);
      oq = __builtin_amdgcn_mfma_f32_16x16x32_bf16(xh, bhi, oq, 0, 0, 0);
      oq = __builtin_amdgcn_mfma_f32_16x16x32_bf16(xl, bhi, oq, 0, 0, 0);
      oq = __builtin_amdgcn_mfma_f32_16x16x32_bf16(xh, blo, oq, 0, 0, 0);
    }
  }

  #pragma unroll
  for (int dt = 0; dt < 4; ++dt)
    #pragma unroll
    for (int r = 0; r < 4; ++r) {
      int oc = 64 * w + dt * 16 + quad * 4 + r;
      vb[((size_t)b * C_ + oc) * N_ + n0 + m] = f2bf(ov[dt][r] + bv[oc]);
    }
  {
    u16* qk_out = (w < 2) ? qt : kt;
    int dbase = (w & 1) * 16;
    float bias = (w < 2) ? bq[dbase + m] * LOG2E : bk[dbase + m];
    #pragma unroll
    for (int r = 0; r < 4; ++r)
      qk_out[((size_t)b * N_ + n0 + quad * 4 + r) * C8_ + dbase + m] =
          f2bf(oq[r] + bias);
  }
}

// ---------------------------------------------------------------------------
// MFMA flash attention, split-K=4, TJ=128, exp2 softmax.
// Register-residency-trimmed fragment loads (K and V in halves) to target
// 3 waves/SIMD (r8 showed 2-wave register cap, not grid cap).
// grid (N/64, 4, B) linearized+swizzled; block 256 (4 waves).
// ---------------------------------------------------------------------------
__global__ __launch_bounds__(256) void attn_mfma(
    const u16* __restrict__ qt, const u16* __restrict__ kt,
    const u16* __restrict__ vb,
    u16* __restrict__ Onorm, float* __restrict__ ml)
{
  __shared__ __align__(16) u16  ps[2][64][136];
  __shared__ __align__(16) float als[2][64];
  __shared__ float lfin[64];

  const int tid = threadIdx.x, lane = tid & 63, w = tid >> 6;
  const int m = lane & 15, quad = lane >> 4;

  const int lid = blockIdx.x + gridDim.x * (blockIdx.y + gridDim.y * blockIdx.z);
  const int grp = lid & 15, ksl = grp & 3, b = grp >> 2;
  const int i0 = (lid >> 4) * 64;

  const bf16x8 qfrag =
      *(const bf16x8*)(qt + ((size_t)b * N_ + i0 + w * 16 + m) * C8_ + quad * 8);
  const u16* kbase = kt + (size_t)b * N_ * C8_;
  const u16* vrow  = vb + ((size_t)b * C_ + w * 64 + m) * N_;

  f32x4 o[4][4];
  #pragma unroll
  for (int t = 0; t < 4; ++t)
    #pragma unroll
    for (int ct = 0; ct < 4; ++ct) o[t][ct] = (f32x4){0.f, 0.f, 0.f, 0.f};
  float m_r = -1e30f, l_r = 0.f;

  const int jbeg = ksl * 1024, jend = jbeg + 1024;
  int buf = 0;

  for (int j0 = jbeg; j0 < jend; j0 += 128, buf ^= 1) {
    // --- S, K in two register halves (peak 16 K-regs instead of 32)
    f32x4 s[8];
    bf16x8 kA[4];
    #pragma unroll
    for (int t = 0; t < 4; ++t)
      kA[t] = *(const bf16x8*)(kbase + (size_t)(j0 + t * 16 + m) * C8_ + quad * 8);
    #pragma unroll
    for (int t = 0; t < 4; ++t)
      s[t] = __builtin_amdgcn_mfma_f32_16x16x32_bf16(
          kA[t], qfrag, (f32x4){0.f, 0.f, 0.f, 0.f}, 0, 0, 0);
    // V first half (kk=0,1) issued here: consumed after the barrier
    bf16x8 vB[4][2];
    #pragma unroll
    for (int ct = 0; ct < 4; ++ct)
      #pragma unroll
      for (int kk = 0; kk < 2; ++kk)
        vB[ct][kk] = *(const bf16x8*)(vrow + (size_t)ct * 16 * N_ + j0 + kk * 32 + quad * 8);
    #pragma unroll
    for (int t = 0; t < 4; ++t)
      kA[t] = *(const bf16x8*)(kbase + (size_t)(j0 + (t + 4) * 16 + m) * C8_ + quad * 8);
    #pragma unroll
    for (int t = 0; t < 4; ++t)
      s[t + 4] = __builtin_amdgcn_mfma_f32_16x16x32_bf16(
          kA[t], qfrag, (f32x4){0.f, 0.f, 0.f, 0.f}, 0, 0, 0);

    // --- register online softmax (log2 domain; q pre-scaled by log2e)
    float mx = -1e30f;
    #pragma unroll
    for (int t = 0; t < 8; ++t)
      #pragma unroll
      for (int r = 0; r < 4; ++r) mx = fmaxf(mx, s[t][r]);
    mx = fmaxf(mx, __shfl_xor(mx, 16));
    mx = fmaxf(mx, __shfl_xor(mx, 32));
    float mn = fmaxf(m_r, mx);
    float al = exp2f(m_r - mn);
    m_r = mn;
    float p[8][4], sm = 0.f;
    #pragma unroll
    for (int t = 0; t < 8; ++t)
      #pragma unroll
      for (int r = 0; r < 4; ++r) {
        p[t][r] = exp2f(s[t][r] - mn);
        sm += p[t][r];
      }
    sm += __shfl_xor(sm, 16);
    sm += __shfl_xor(sm, 32);
    l_r = l_r * al + sm;

    #pragma unroll
    for (int t = 0; t < 8; ++t)
      *(uint2*)&ps[buf][w * 16 + m][t * 16 + quad * 4] =
          make_uint2(pack_rtz(p[t][0], p[t][1]), pack_rtz(p[t][2], p[t][3]));
    if (quad == 0) als[buf][w * 16 + m] = al;

    lds_barrier();   // LDS visibility only; V loads stay outstanding

    // --- rescale O
    #pragma unroll
    for (int t = 0; t < 4; ++t) {
      float4 alv = *(const float4*)&als[buf][t * 16 + quad * 4];
      #pragma unroll
      for (int ct = 0; ct < 4; ++ct) {
        o[t][ct][0] *= alv.x; o[t][ct][1] *= alv.y;
        o[t][ct][2] *= alv.z; o[t][ct][3] *= alv.w;
      }
    }

    // --- PV kk = 0,1
    #pragma unroll
    for (int kk = 0; kk < 2; ++kk)
      #pragma unroll
      for (int t = 0; t < 4; ++t) {
        bf16x8 pf = *(const bf16x8*)&ps[buf][t * 16 + m][kk * 32 + quad * 8];
        #pragma unroll
        for (int ct = 0; ct < 4; ++ct)
          o[t][ct] = __builtin_amdgcn_mfma_f32_16x16x32_bf16(pf, vB[ct][kk], o[t][ct], 0, 0, 0);
      }

    // pin: reload of V (kk=2,3) must NOT be hoisted above PV kk=0,1
    __builtin_amdgcn_sched_barrier(0);

    #pragma unroll
    for (int ct = 0; ct < 4; ++ct)
      #pragma unroll
      for (int kk = 0; kk < 2; ++kk)
        vB[ct][kk] = *(const bf16x8*)(vrow + (size_t)ct * 16 * N_ + j0 + (kk + 2) * 32 + quad * 8);

    // --- PV kk = 2,3
    #pragma unroll
    for (int kk = 0; kk < 2; ++kk)
      #pragma unroll
      for (int t = 0; t < 4; ++t) {
        bf16x8 pf = *(const bf16x8*)&ps[buf][t * 16 + m][(kk + 2) * 32 + quad * 8];
        #pragma unroll
        for (int ct = 0; ct < 4; ++ct)
          o[t][ct] = __builtin_amdgcn_mfma_f32_16x16x32_bf16(pf, vB[ct][kk], o[t][ct], 0, 0, 0);
      }
  }

  // share 1/l across waves (O rows span all 64 block queries)
  if (quad == 0) lfin[w * 16 + m] = 1.f / l_r;
  lds_barrier();

  u16* Ob = Onorm + (((size_t)ksl * B_ + b) * N_ + i0) * C_ + w * 64;
  #pragma unroll
  for (int t = 0; t < 4; ++t) {
    float4 lv = *(const float4*)&lfin[t * 16 + quad * 4];
    float linv[4] = {lv.x, lv.y, lv.z, lv.w};
    #pragma unroll
    for (int ct = 0; ct < 4; ++ct)
      #pragma unroll
      for (int r = 0; r < 4; ++r)
        Ob[(size_t)(t * 16 + quad * 4 + r) * C_ + ct * 16 + m] = f2bf(o[t][ct][r] * linv[r]);
  }

  if (quad == 0) {
    size_t mli = ((size_t)ksl * B_ + b) * N_ + i0 + w * 16 + m;
    ml[mli] = m_r;
    ml[(size_t)4 * B_ * N_ + mli] = l_r;
  }
}

// ---------------------------------------------------------------------------
// Fused split-K combine + residual + final 1x1 conv.  16-pixel tiles.
// grid (N/16, B), block 256 -> 1024 blocks (4/CU).
// ---------------------------------------------------------------------------
__global__ __launch_bounds__(256) void out_mfma(
    const u16* __restrict__ Onorm, const float* __restrict__ ml,
    const u16* __restrict__ xTh,
    const u16* __restrict__ WoH, const u16* __restrict__ WoL,
    const float* __restrict__ bo, float* __restrict__ out)
{
  __shared__ __align__(16) u16 hs[16][270];

  const int tid = threadIdx.x;
  const int lane = tid & 63, w = tid >> 6, m = lane & 15, quad = lane >> 4;
  const int b = blockIdx.y, n0 = blockIdx.x * 16;
  constexpr size_t BN = (size_t)B_ * N_;

  #pragma unroll
  for (int it = 0; it < 2; ++it) {
    int chunk = tid + it * 256;
    int row = chunk >> 5, col = (chunk & 31) * 8;
    size_t nrow = (size_t)b * N_ + n0 + row;

    float mm0 = ml[nrow], mm1 = ml[BN + nrow], mm2 = ml[2 * BN + nrow], mm3 = ml[3 * BN + nrow];
    float M = fmaxf(fmaxf(mm0, mm1), fmaxf(mm2, mm3));
    float ws[4];
    ws[0] = ml[4 * BN + nrow] * exp2f(mm0 - M);
    ws[1] = ml[5 * BN + nrow] * exp2f(mm1 - M);
    ws[2] = ml[6 * BN + nrow] * exp2f(mm2 - M);
    ws[3] = ml[7 * BN + nrow] * exp2f(mm3 - M);
    float inv = 1.f / (ws[0] + ws[1] + ws[2] + ws[3]);
    #pragma unroll
    for (int s = 0; s < 4; ++s) ws[s] *= inv;

    uint4 xv = *(const uint4*)(xTh + nrow * C_ + col);
    u32 xq[4] = {xv.x, xv.y, xv.z, xv.w};
    float acc[8];
    #pragma unroll
    for (int j = 0; j < 4; ++j) {
      acc[2 * j]     = bf2f((u16)(xq[j] & 0xffff));
      acc[2 * j + 1] = bf2f((u16)(xq[j] >> 16));
    }
    #pragma unroll
    for (int s = 0; s < 4; ++s) {
      uint4 ovv = *(const uint4*)(Onorm + (s * BN + nrow) * C_ + col);
      u32 oq[4] = {ovv.x, ovv.y, ovv.z, ovv.w};
      #pragma unroll
      for (int j = 0; j < 4; ++j) {
        acc[2 * j]     += ws[s] * bf2f((u16)(oq[j] & 0xffff));
        acc[2 * j + 1] += ws[s] * bf2f((u16)(oq[j] >> 16));
      }
    }
    uint4 pk;
    pk.x = (u32)f2bf(acc[0]) | ((u32)f2bf(acc[1]) << 16);
    pk.y = (u32)f2bf(acc[2]) | ((u32)f2bf(acc[3]) << 16);
    pk.z = (u32)f2bf(acc[4]) | ((u32)f2bf(acc[5]) << 16);
    pk.w = (u32)f2bf(acc[6]) | ((u32)f2bf(acc[7]) << 16);
    *(uint4*)&hs[row][col] = pk;
  }
  __syncthreads();

  f32x4 o[4];
  #pragma unroll
  for (int dt = 0; dt < 4; ++dt) o[dt] = (f32x4){0.f, 0.f, 0.f, 0.f};

  for (int K = 0; K < 8; ++K) {
    const int ko = K * 32 + quad * 8;
    bf16x8 hf = *(const bf16x8*)&hs[m][ko];
    #pragma unroll
    for (int dt = 0; dt < 4; ++dt) {
      bf16x8 whi = *(const bf16x8*)(WoH + (size_t)(64 * w + dt * 16 + m) * C_ + ko);
      bf16x8 wlo = *(const bf16x8*)(WoL + (size_t)(64 * w + dt * 16 + m) * C_ + ko);
      o[dt] = __builtin_amdgcn_mfma_f32_16x16x32_bf16(whi, hf, o[dt], 0, 0, 0);
      o[dt] = __builtin_amdgcn_mfma_f32_16x16x32_bf16(wlo, hf, o[dt], 0, 0, 0);
    }
  }

  #pragma unroll
  for (int dt = 0; dt < 4; ++dt)
    #pragma unroll
    for (int r = 0; r < 4; ++r) {
      int d = 64 * w + dt * 16 + quad * 4 + r;
      out[((size_t)b * C_ + d) * N_ + n0 + m] = o[dt][r] + bo[d];
    }
}

// ---------------------------------------------------------------------------
extern "C" void kernel_launch(void* const* d_in, const int* in_sizes, int n_in,
                              void* d_out, int out_size, void* d_ws, size_t ws_size,
                              hipStream_t stream)
{
  const float* x  = (const float*)d_in[0];
  const float* Wq = (const float*)d_in[1];
  const float* bq = (const float*)d_in[2];
  const float* Wk = (const float*)d_in[3];
  const float* bk = (const float*)d_in[4];
  const float* Wv = (const float*)d_in[5];
  const float* bv = (const float*)d_in[6];
  const float* Wo = (const float*)d_in[7];
  const float* bo = (const float*)d_in[8];

  // workspace (~53 MB). Onorm ALIASES xTl (dead after qkv_mfma).
  u16* p = (u16*)d_ws;
  u16* qt  = p;  p += (size_t)B_ * N_ * C8_;   // 1 MB
  u16* kt  = p;  p += (size_t)B_ * N_ * C8_;   // 1 MB
  u16* vb  = p;  p += (size_t)B_ * C_ * N_;    // 8 MB
  u16* xTh = p;  p += (size_t)B_ * N_ * C_;    // 8 MB
  u16* WqH = p;  p += 8192;
  u16* WqL = p;  p += 8192;
  u16* WkH = p;  p += 8192;
  u16* WkL = p;  p += 8192;
  u16* WvH = p;  p += 65536;
  u16* WoH = p;  p += 65536;
  u16* WoL = p;  p += 65536;
  float* ml = (float*)p;  p += (size_t)16 * B_ * N_;  // 8*BN floats = 512 KB
  u16* xTl   = p;                               // 8 MB (dead after qkv)
  u16* Onorm = p;                               // 33.5 MB (4,B,N,C) bf16

  float* out = (float*)d_out;

  wsplit<<<576, 256, 0, stream>>>(Wq, Wk, Wv, Wo,
      WqH, WqL, WkH, WkL, WvH, WoH, WoL);
  xprep<<<dim3(N_ / 64, C_ / 64, B_), 256, 0, stream>>>(x, xTh, xTl);
  qkv_mfma<<<dim3(N_ / 16, B_), 256, 0, stream>>>(
      xTh, xTl, WqH, WqL, WkH, WkL, WvH, bq, bk, bv, qt, kt, vb);
  attn_mfma<<<dim3(N_ / 64, 4, B_), 256, 0, stream>>>(qt, kt, vb, Onorm, ml);
  out_mfma<<<dim3(N_ / 16, B_), 256, 0, stream>>>(Onorm, ml, xTh, WoH, WoL, bo, out);
}

// Round 10
// 203.034 us; speedup vs baseline: 1.1339x; 1.1339x over previous
//
#include <hip/hip_runtime.h>

#define DEV __device__ __forceinline__

constexpr int B_  = 4;
constexpr int C_  = 256;
constexpr int C8_ = 32;
constexpr int N_  = 4096;   // 64*64
constexpr float LOG2E = 1.4426950408889634f;

using u16 = unsigned short;
using u32 = unsigned int;

typedef __attribute__((ext_vector_type(8))) short bf16x8;
typedef __attribute__((ext_vector_type(4))) float f32x4;

DEV float bf2f(u16 u) { return __uint_as_float(((u32)u) << 16); }
DEV u16   f2bf(float f) {
  u32 i = __float_as_uint(f);
  i += 0x7fffu + ((i >> 16) & 1u);   // round-to-nearest-even
  return (u16)(i >> 16);
}
// pack two floats to bf16x2 (RTZ) in ONE v_perm_b32
DEV u32 pack_rtz(float a, float b) {
  return __builtin_amdgcn_perm(__float_as_uint(b), __float_as_uint(a), 0x07060302);
}

// LDS-only barrier: cross-wave data is in LDS only -> skip the vmcnt(0) drain
DEV void lds_barrier() {
  asm volatile("s_waitcnt lgkmcnt(0)\n\ts_barrier" ::: "memory");
}

// ---------------------------------------------------------------------------
// Fused prep: blocks [0,576) split weights; blocks [576,1600) transpose x.
//   Wq*log2e, Wk -> hi/lo; Wv -> hi; Wo -> hi/lo.
//   x (B,C,N) f32 -> xTh, xTl (B,N,C) bf16 hi/lo.
// ---------------------------------------------------------------------------
__global__ __launch_bounds__(256) void prep(
    const float* __restrict__ Wq, const float* __restrict__ Wk,
    const float* __restrict__ Wv, const float* __restrict__ Wo,
    const float* __restrict__ x,
    u16* __restrict__ WqH, u16* __restrict__ WqL,
    u16* __restrict__ WkH, u16* __restrict__ WkL,
    u16* __restrict__ WvH,
    u16* __restrict__ WoH, u16* __restrict__ WoL,
    u16* __restrict__ xTh, u16* __restrict__ xTl)
{
  __shared__ float tf[64][65];
  const int tid = threadIdx.x;

  if (blockIdx.x < 576) {
    int i = blockIdx.x * 256 + tid;
    if (i < 8192) {
      float v = Wq[i] * LOG2E;
      u16 h = f2bf(v); WqH[i] = h; WqL[i] = f2bf(v - bf2f(h));
    } else if (i < 16384) {
      int off = i - 8192;
      float v = Wk[off];
      u16 h = f2bf(v); WkH[off] = h; WkL[off] = f2bf(v - bf2f(h));
    } else if (i < 81920) {
      int off = i - 16384;
      WvH[off] = f2bf(Wv[off]);
    } else {
      int off = i - 81920;
      float v = Wo[off];
      u16 h = f2bf(v); WoH[off] = h; WoL[off] = f2bf(v - bf2f(h));
    }
    return;
  }

  const int lid = blockIdx.x - 576;          // [0,1024)
  const int b  = lid >> 8;
  const int c0 = ((lid >> 6) & 3) * 64;
  const int n0 = (lid & 63) * 64;
  const int nl = tid & 63, cb = tid >> 6;

  #pragma unroll
  for (int cc = 0; cc < 16; ++cc) {
    int cl = cb * 16 + cc;
    tf[nl][cl] = x[((size_t)b * C_ + c0 + cl) * N_ + n0 + nl];
  }
  __syncthreads();

  #pragma unroll
  for (int it = 0; it < 2; ++it) {
    int idx = tid + it * 256;
    int n = idx >> 3, q = idx & 7;
    u32 ph[4], pl[4];
    #pragma unroll
    for (int j = 0; j < 4; ++j) {
      float v0 = tf[n][q * 8 + 2 * j], v1 = tf[n][q * 8 + 2 * j + 1];
      u16 h0 = f2bf(v0), h1 = f2bf(v1);
      ph[j] = (u32)h0 | ((u32)h1 << 16);
      pl[j] = (u32)f2bf(v0 - bf2f(h0)) | ((u32)f2bf(v1 - bf2f(h1)) << 16);
    }
    size_t off = ((size_t)b * N_ + n0 + n) * C_ + c0 + q * 8;
    *(uint4*)&xTh[off] = make_uint4(ph[0], ph[1], ph[2], ph[3]);
    *(uint4*)&xTl[off] = make_uint4(pl[0], pl[1], pl[2], pl[3]);
  }
}

// ---------------------------------------------------------------------------
// q/k/v projections, LDS-staged x fragments.  32-pixel tiles (r8 shape).
// grid (N/32, B), block 256.
// ---------------------------------------------------------------------------
__global__ __launch_bounds__(256) void qkv_mfma(
    const u16* __restrict__ xTh, const u16* __restrict__ xTl,
    const u16* __restrict__ WqH, const u16* __restrict__ WqL,
    const u16* __restrict__ WkH, const u16* __restrict__ WkL,
    const u16* __restrict__ WvH,
    const float* __restrict__ bq, const float* __restrict__ bk,
    const float* __restrict__ bv,
    u16* __restrict__ qt, u16* __restrict__ kt, u16* __restrict__ vb)
{
  __shared__ __align__(16) u16 xsh[32][270];
  __shared__ __align__(16) u16 xsl[32][270];

  const int tid = threadIdx.x;
  const int lane = tid & 63, w = tid >> 6, m = lane & 15, quad = lane >> 4;
  const int b = blockIdx.y, n0 = blockIdx.x * 32;

  #pragma unroll
  for (int it = 0; it < 4; ++it) {
    int chunk = tid + it * 256;
    int row = chunk >> 5, col = (chunk & 31) * 8;
    size_t g = ((size_t)b * N_ + n0 + row) * C_ + col;
    *(uint4*)&xsh[row][col] = *(const uint4*)(xTh + g);
    *(uint4*)&xsl[row][col] = *(const uint4*)(xTl + g);
  }
  __syncthreads();

  const u16* qkH = (w < 2) ? (WqH + (size_t)(w * 16 + m) * C_)
                           : (WkH + (size_t)((w - 2) * 16 + m) * C_);
  const u16* qkL = (w < 2) ? (WqL + (size_t)(w * 16 + m) * C_)
                           : (WkL + (size_t)((w - 2) * 16 + m) * C_);

  f32x4 ov[4][2], oq[2];
  #pragma unroll
  for (int dt = 0; dt < 4; ++dt)
    #pragma unroll
    for (int nt = 0; nt < 2; ++nt) ov[dt][nt] = (f32x4){0.f, 0.f, 0.f, 0.f};
  #pragma unroll
  for (int nt = 0; nt < 2; ++nt) oq[nt] = (f32x4){0.f, 0.f, 0.f, 0.f};

  for (int K = 0; K < 8; ++K) {
    const int ko = K * 32 + quad * 8;
    bf16x8 xh[2], xl[2];
    #pragma unroll
    for (int nt = 0; nt < 2; ++nt) {
      xh[nt] = *(const bf16x8*)&xsh[nt * 16 + m][ko];
      xl[nt] = *(const bf16x8*)&xsl[nt * 16 + m][ko];
    }
    #pragma unroll
    for (int dt = 0; dt < 4; ++dt) {
      bf16x8 whi = *(const bf16x8*)(WvH + (size_t)(64 * w + dt * 16 + m) * C_ + ko);
      #pragma unroll
      for (int nt = 0; nt < 2; ++nt)
        ov[dt][nt] = __builtin_amdgcn_mfma_f32_16x16x32_bf16(whi, xh[nt], ov[dt][nt], 0, 0, 0);
    }
    {
      bf16x8 bhi = *(const bf16x8*)(qkH + ko);
      bf16x8 blo = *(const bf16x8*)(qkL + ko);
      #pragma unroll
      for (int nt = 0; nt < 2; ++nt) {
        oq[nt] = __builtin_amdgcn_mfma_f32_16x16x32_bf16(xh[nt], bhi, oq[nt], 0, 0, 0);
        oq[nt] = __builtin_amdgcn_mfma_f32_16x16x32_bf16(xl[nt], bhi, oq[nt], 0, 0, 0);
        oq[nt] = __builtin_amdgcn_mfma_f32_16x16x32_bf16(xh[nt], blo, oq[nt], 0, 0, 0);
      }
    }
  }

  #pragma unroll
  for (int dt = 0; dt < 4; ++dt)
    #pragma unroll
    for (int r = 0; r < 4; ++r) {
      int oc = 64 * w + dt * 16 + quad * 4 + r;
      float bias = bv[oc];
      #pragma unroll
      for (int nt = 0; nt < 2; ++nt)
        vb[((size_t)b * C_ + oc) * N_ + n0 + nt * 16 + m] = f2bf(ov[dt][nt][r] + bias);
    }
  {
    u16* qk_out = (w < 2) ? qt : kt;
    int dbase = (w & 1) * 16;
    float bias = (w < 2) ? bq[dbase + m] * LOG2E : bk[dbase + m];
    #pragma unroll
    for (int nt = 0; nt < 2; ++nt)
      #pragma unroll
      for (int r = 0; r < 4; ++r)
        qk_out[((size_t)b * N_ + n0 + nt * 16 + quad * 4 + r) * C8_ + dbase + m] =
            f2bf(oq[nt][r] + bias);
  }
}

// ---------------------------------------------------------------------------
// MFMA flash attention, split-K=4, TJ=128, exp2 softmax.
// In-place softmax on s[] (p[] eliminated) to cut ~32 VGPR -> target
// 3 waves/SIMD (r8/r9 showed 2-wave unified-register cap).
// grid (N/64, 4, B) linearized+swizzled; block 256 (4 waves).
// ---------------------------------------------------------------------------
__global__ __launch_bounds__(256) void attn_mfma(
    const u16* __restrict__ qt, const u16* __restrict__ kt,
    const u16* __restrict__ vb,
    u16* __restrict__ Onorm, float* __restrict__ ml)
{
  __shared__ __align__(16) u16  ps[2][64][136];
  __shared__ __align__(16) float als[2][64];
  __shared__ float lfin[64];

  const int tid = threadIdx.x, lane = tid & 63, w = tid >> 6;
  const int m = lane & 15, quad = lane >> 4;

  const int lid = blockIdx.x + gridDim.x * (blockIdx.y + gridDim.y * blockIdx.z);
  const int grp = lid & 15, ksl = grp & 3, b = grp >> 2;
  const int i0 = (lid >> 4) * 64;

  const bf16x8 qfrag =
      *(const bf16x8*)(qt + ((size_t)b * N_ + i0 + w * 16 + m) * C8_ + quad * 8);
  const u16* kbase = kt + (size_t)b * N_ * C8_;
  const u16* vrow  = vb + ((size_t)b * C_ + w * 64 + m) * N_;

  f32x4 o[4][4];
  #pragma unroll
  for (int t = 0; t < 4; ++t)
    #pragma unroll
    for (int ct = 0; ct < 4; ++ct) o[t][ct] = (f32x4){0.f, 0.f, 0.f, 0.f};
  float m_r = -1e30f, l_r = 0.f;

  const int jbeg = ksl * 1024, jend = jbeg + 1024;
  int buf = 0;

  for (int j0 = jbeg; j0 < jend; j0 += 128, buf ^= 1) {
    // --- S, K in two register halves (peak 16 K-regs instead of 32)
    f32x4 s[8];
    bf16x8 kA[4];
    #pragma unroll
    for (int t = 0; t < 4; ++t)
      kA[t] = *(const bf16x8*)(kbase + (size_t)(j0 + t * 16 + m) * C8_ + quad * 8);
    #pragma unroll
    for (int t = 0; t < 4; ++t)
      s[t] = __builtin_amdgcn_mfma_f32_16x16x32_bf16(
          kA[t], qfrag, (f32x4){0.f, 0.f, 0.f, 0.f}, 0, 0, 0);
    // V first half (kk=0,1) issued here: consumed after the barrier
    bf16x8 vB[4][2];
    #pragma unroll
    for (int ct = 0; ct < 4; ++ct)
      #pragma unroll
      for (int kk = 0; kk < 2; ++kk)
        vB[ct][kk] = *(const bf16x8*)(vrow + (size_t)ct * 16 * N_ + j0 + kk * 32 + quad * 8);
    #pragma unroll
    for (int t = 0; t < 4; ++t)
      kA[t] = *(const bf16x8*)(kbase + (size_t)(j0 + (t + 4) * 16 + m) * C8_ + quad * 8);
    #pragma unroll
    for (int t = 0; t < 4; ++t)
      s[t + 4] = __builtin_amdgcn_mfma_f32_16x16x32_bf16(
          kA[t], qfrag, (f32x4){0.f, 0.f, 0.f, 0.f}, 0, 0, 0);

    // --- register online softmax, IN-PLACE on s (log2 domain)
    float mx = -1e30f;
    #pragma unroll
    for (int t = 0; t < 8; ++t)
      #pragma unroll
      for (int r = 0; r < 4; ++r) mx = fmaxf(mx, s[t][r]);
    mx = fmaxf(mx, __shfl_xor(mx, 16));
    mx = fmaxf(mx, __shfl_xor(mx, 32));
    float mn = fmaxf(m_r, mx);
    float al = exp2f(m_r - mn);
    m_r = mn;
    float sm = 0.f;
    #pragma unroll
    for (int t = 0; t < 8; ++t)
      #pragma unroll
      for (int r = 0; r < 4; ++r) {
        s[t][r] = exp2f(s[t][r] - mn);
        sm += s[t][r];
      }
    sm += __shfl_xor(sm, 16);
    sm += __shfl_xor(sm, 32);
    l_r = l_r * al + sm;

    #pragma unroll
    for (int t = 0; t < 8; ++t)
      *(uint2*)&ps[buf][w * 16 + m][t * 16 + quad * 4] =
          make_uint2(pack_rtz(s[t][0], s[t][1]), pack_rtz(s[t][2], s[t][3]));
    if (quad == 0) als[buf][w * 16 + m] = al;

    lds_barrier();   // LDS visibility only; V loads stay outstanding

    // --- rescale O
    #pragma unroll
    for (int t = 0; t < 4; ++t) {
      float4 alv = *(const float4*)&als[buf][t * 16 + quad * 4];
      #pragma unroll
      for (int ct = 0; ct < 4; ++ct) {
        o[t][ct][0] *= alv.x; o[t][ct][1] *= alv.y;
        o[t][ct][2] *= alv.z; o[t][ct][3] *= alv.w;
      }
    }

    // --- PV kk = 0,1
    #pragma unroll
    for (int kk = 0; kk < 2; ++kk)
      #pragma unroll
      for (int t = 0; t < 4; ++t) {
        bf16x8 pf = *(const bf16x8*)&ps[buf][t * 16 + m][kk * 32 + quad * 8];
        #pragma unroll
        for (int ct = 0; ct < 4; ++ct)
          o[t][ct] = __builtin_amdgcn_mfma_f32_16x16x32_bf16(pf, vB[ct][kk], o[t][ct], 0, 0, 0);
      }

    // pin: reload of V (kk=2,3) must NOT be hoisted above PV kk=0,1
    __builtin_amdgcn_sched_barrier(0);

    #pragma unroll
    for (int ct = 0; ct < 4; ++ct)
      #pragma unroll
      for (int kk = 0; kk < 2; ++kk)
        vB[ct][kk] = *(const bf16x8*)(vrow + (size_t)ct * 16 * N_ + j0 + (kk + 2) * 32 + quad * 8);

    // --- PV kk = 2,3
    #pragma unroll
    for (int kk = 0; kk < 2; ++kk)
      #pragma unroll
      for (int t = 0; t < 4; ++t) {
        bf16x8 pf = *(const bf16x8*)&ps[buf][t * 16 + m][(kk + 2) * 32 + quad * 8];
        #pragma unroll
        for (int ct = 0; ct < 4; ++ct)
          o[t][ct] = __builtin_amdgcn_mfma_f32_16x16x32_bf16(pf, vB[ct][kk], o[t][ct], 0, 0, 0);
      }
  }

  // share 1/l across waves (O rows span all 64 block queries)
  if (quad == 0) lfin[w * 16 + m] = 1.f / l_r;
  lds_barrier();

  u16* Ob = Onorm + (((size_t)ksl * B_ + b) * N_ + i0) * C_ + w * 64;
  #pragma unroll
  for (int t = 0; t < 4; ++t) {
    float4 lv = *(const float4*)&lfin[t * 16 + quad * 4];
    float linv[4] = {lv.x, lv.y, lv.z, lv.w};
    #pragma unroll
    for (int ct = 0; ct < 4; ++ct)
      #pragma unroll
      for (int r = 0; r < 4; ++r)
        Ob[(size_t)(t * 16 + quad * 4 + r) * C_ + ct * 16 + m] = f2bf(o[t][ct][r] * linv[r]);
  }

  if (quad == 0) {
    size_t mli = ((size_t)ksl * B_ + b) * N_ + i0 + w * 16 + m;
    ml[mli] = m_r;
    ml[(size_t)4 * B_ * N_ + mli] = l_r;
  }
}

// ---------------------------------------------------------------------------
// Fused split-K combine + residual + final 1x1 conv.  32-pixel tiles (r8).
// grid (N/32, B), block 256.
// ---------------------------------------------------------------------------
__global__ __launch_bounds__(256) void out_mfma(
    const u16* __restrict__ Onorm, const float* __restrict__ ml,
    const u16* __restrict__ xTh,
    const u16* __restrict__ WoH, const u16* __restrict__ WoL,
    const float* __restrict__ bo, float* __restrict__ out)
{
  __shared__ __align__(16) u16 hs[32][270];

  const int tid = threadIdx.x;
  const int lane = tid & 63, w = tid >> 6, m = lane & 15, quad = lane >> 4;
  const int b = blockIdx.y, n0 = blockIdx.x * 32;
  constexpr size_t BN = (size_t)B_ * N_;

  #pragma unroll
  for (int it = 0; it < 4; ++it) {
    int chunk = tid + it * 256;
    int row = chunk >> 5, col = (chunk & 31) * 8;
    size_t nrow = (size_t)b * N_ + n0 + row;

    float mm0 = ml[nrow], mm1 = ml[BN + nrow], mm2 = ml[2 * BN + nrow], mm3 = ml[3 * BN + nrow];
    float M = fmaxf(fmaxf(mm0, mm1), fmaxf(mm2, mm3));
    float ws[4];
    ws[0] = ml[4 * BN + nrow] * exp2f(mm0 - M);
    ws[1] = ml[5 * BN + nrow] * exp2f(mm1 - M);
    ws[2] = ml[6 * BN + nrow] * exp2f(mm2 - M);
    ws[3] = ml[7 * BN + nrow] * exp2f(mm3 - M);
    float inv = 1.f / (ws[0] + ws[1] + ws[2] + ws[3]);
    #pragma unroll
    for (int s = 0; s < 4; ++s) ws[s] *= inv;

    uint4 xv = *(const uint4*)(xTh + nrow * C_ + col);
    u32 xq[4] = {xv.x, xv.y, xv.z, xv.w};
    float acc[8];
    #pragma unroll
    for (int j = 0; j < 4; ++j) {
      acc[2 * j]     = bf2f((u16)(xq[j] & 0xffff));
      acc[2 * j + 1] = bf2f((u16)(xq[j] >> 16));
    }
    #pragma unroll
    for (int s = 0; s < 4; ++s) {
      uint4 ovv = *(const uint4*)(Onorm + (s * BN + nrow) * C_ + col);
      u32 oq[4] = {ovv.x, ovv.y, ovv.z, ovv.w};
      #pragma unroll
      for (int j = 0; j < 4; ++j) {
        acc[2 * j]     += ws[s] * bf2f((u16)(oq[j] & 0xffff));
        acc[2 * j + 1] += ws[s] * bf2f((u16)(oq[j] >> 16));
      }
    }
    uint4 pk;
    pk.x = (u32)f2bf(acc[0]) | ((u32)f2bf(acc[1]) << 16);
    pk.y = (u32)f2bf(acc[2]) | ((u32)f2bf(acc[3]) << 16);
    pk.z = (u32)f2bf(acc[4]) | ((u32)f2bf(acc[5]) << 16);
    pk.w = (u32)f2bf(acc[6]) | ((u32)f2bf(acc[7]) << 16);
    *(uint4*)&hs[row][col] = pk;
  }
  __syncthreads();

  f32x4 o[4][2];
  #pragma unroll
  for (int dt = 0; dt < 4; ++dt)
    #pragma unroll
    for (int nt = 0; nt < 2; ++nt) o[dt][nt] = (f32x4){0.f, 0.f, 0.f, 0.f};

  for (int K = 0; K < 8; ++K) {
    const int ko = K * 32 + quad * 8;
    bf16x8 hf[2];
    #pragma unroll
    for (int nt = 0; nt < 2; ++nt) hf[nt] = *(const bf16x8*)&hs[nt * 16 + m][ko];
    #pragma unroll
    for (int dt = 0; dt < 4; ++dt) {
      bf16x8 whi = *(const bf16x8*)(WoH + (size_t)(64 * w + dt * 16 + m) * C_ + ko);
      bf16x8 wlo = *(const bf16x8*)(WoL + (size_t)(64 * w + dt * 16 + m) * C_ + ko);
      #pragma unroll
      for (int nt = 0; nt < 2; ++nt) {
        o[dt][nt] = __builtin_amdgcn_mfma_f32_16x16x32_bf16(whi, hf[nt], o[dt][nt], 0, 0, 0);
        o[dt][nt] = __builtin_amdgcn_mfma_f32_16x16x32_bf16(wlo, hf[nt], o[dt][nt], 0, 0, 0);
      }
    }
  }

  #pragma unroll
  for (int dt = 0; dt < 4; ++dt)
    #pragma unroll
    for (int r = 0; r < 4; ++r) {
      int d = 64 * w + dt * 16 + quad * 4 + r;
      float bias = bo[d];
      #pragma unroll
      for (int nt = 0; nt < 2; ++nt)
        out[((size_t)b * C_ + d) * N_ + n0 + nt * 16 + m] = o[dt][nt][r] + bias;
    }
}

// ---------------------------------------------------------------------------
extern "C" void kernel_launch(void* const* d_in, const int* in_sizes, int n_in,
                              void* d_out, int out_size, void* d_ws, size_t ws_size,
                              hipStream_t stream)
{
  const float* x  = (const float*)d_in[0];
  const float* Wq = (const float*)d_in[1];
  const float* bq = (const float*)d_in[2];
  const float* Wk = (const float*)d_in[3];
  const float* bk = (const float*)d_in[4];
  const float* Wv = (const float*)d_in[5];
  const float* bv = (const float*)d_in[6];
  const float* Wo = (const float*)d_in[7];
  const float* bo = (const float*)d_in[8];

  // workspace (~53 MB). Onorm ALIASES xTl (dead after qkv_mfma).
  u16* p = (u16*)d_ws;
  u16* qt  = p;  p += (size_t)B_ * N_ * C8_;   // 1 MB
  u16* kt  = p;  p += (size_t)B_ * N_ * C8_;   // 1 MB
  u16* vb  = p;  p += (size_t)B_ * C_ * N_;    // 8 MB
  u16* xTh = p;  p += (size_t)B_ * N_ * C_;    // 8 MB
  u16* WqH = p;  p += 8192;
  u16* WqL = p;  p += 8192;
  u16* WkH = p;  p += 8192;
  u16* WkL = p;  p += 8192;
  u16* WvH = p;  p += 65536;
  u16* WoH = p;  p += 65536;
  u16* WoL = p;  p += 65536;
  float* ml = (float*)p;  p += (size_t)16 * B_ * N_;  // 8*BN floats = 512 KB
  u16* xTl   = p;                               // 8 MB (dead after qkv)
  u16* Onorm = p;                               // 33.5 MB (4,B,N,C) bf16

  float* out = (float*)d_out;

  prep<<<1600, 256, 0, stream>>>(Wq, Wk, Wv, Wo, x,
      WqH, WqL, WkH, WkL, WvH, WoH, WoL, xTh, xTl);
  qkv_mfma<<<dim3(N_ / 32, B_), 256, 0, stream>>>(
      xTh, xTl, WqH, WqL, WkH, WkL, WvH, bq, bk, bv, qt, kt, vb);
  attn_mfma<<<dim3(N_ / 64, 4, B_), 256, 0, stream>>>(qt, kt, vb, Onorm, ml);
  out_mfma<<<dim3(N_ / 32, B_), 256, 0, stream>>>(Onorm, ml, xTh, WoH, WoL, bo, out);
}